// Round 6
// baseline (1024.342 us; speedup 1.0000x reference)
//
#include <hip/hip_runtime.h>

#define B_ 8
#define C_ 64
#define HW_ 65536
#define SLOPE_ 0.01f
#define EPS_ 1e-5f
#define CROP_ 244
#define NPIX_ 59536.0f

typedef unsigned short u16;
typedef __attribute__((ext_vector_type(8))) _Float16 f16x8;
typedef __attribute__((ext_vector_type(2))) _Float16 f16x2;
typedef __attribute__((ext_vector_type(4))) float f32x4;

__device__ __forceinline__ int clampi(int v, int lo, int hi) { return v < lo ? lo : (v > hi ? hi : v); }
__device__ __forceinline__ float lrelu(float v) { return fmaxf(v, 0.f) + SLOPE_ * fminf(v, 0.f); }

__device__ __forceinline__ u16 f2h(float f) {
    union { _Float16 h; u16 u; } v; v.h = (_Float16)f; return v.u;
}
__device__ __forceinline__ float h2f(u16 b) {
    union { u16 u; _Float16 h; } v; v.u = b; return (float)v.h;
}
__device__ __forceinline__ f16x2 lrelu2(f16x2 a) {
    const f16x2 z = {(_Float16)0.f, (_Float16)0.f};
    const f16x2 sl = {(_Float16)SLOPE_, (_Float16)SLOPE_};
    return __builtin_elementwise_max(a, z) + sl * __builtin_elementwise_min(a, z);
}

// ---- weight pack: ws (7,oc64,ic64,3,3) fp32 -> wH f16 frag-major
// wH[l][tap][kb][mt][lane][j]: oc = mt*16 + (lane&15), ic = kb*32 + (lane>>4)*8 + j
__global__ void wtrans_kernel(const float* __restrict__ ws, u16* __restrict__ wH) {
    int idx = blockIdx.x * 256 + threadIdx.x;
    if (idx >= 7 * 36864) return;
    int l = idx / 36864;
    int rem = idx - l * 36864;
    int frag = rem >> 9;          // tap*8 + kb*4 + mt
    int lj = rem & 511;
    int lane = lj >> 3, j = lj & 7;
    int tap = frag >> 3, kb = (frag >> 2) & 1, mt = frag & 3;
    int oc = (mt << 4) + (lane & 15);
    int ic = (kb << 5) + ((lane >> 4) << 3) + j;
    wH[idx] = f2h(ws[((l * 64 + oc) * 64 + ic) * 9 + tap]);
}

// ---- conv0: 1->64, NHWC f16 output
__global__ __launch_bounds__(256) void conv0_kernel(
    const float* __restrict__ xin, const float* __restrict__ w0,
    const float* __restrict__ b0, u16* __restrict__ yout) {
    __shared__ float w0s[576];
    __shared__ float b0s[64];
    int tid = threadIdx.x;
    for (int i = tid; i < 576; i += 256) w0s[i] = w0[i];
    if (tid < 64) b0s[tid] = b0[tid];
    __syncthreads();
    int pxg = blockIdx.x * 256 + tid;
    int b = pxg >> 16, px = pxg & 65535;
    int y = px >> 8, x = px & 255;
    float xv[9];
#pragma unroll
    for (int ky = 0; ky < 3; ky++)
#pragma unroll
        for (int kx = 0; kx < 3; kx++)
            xv[ky * 3 + kx] = xin[(b << 16) + (clampi(y + ky - 1, 0, 255) << 8) + clampi(x + kx - 1, 0, 255)];
    float acc[64];
#pragma unroll
    for (int k = 0; k < 64; k++) acc[k] = b0s[k];
#pragma unroll
    for (int t = 0; t < 9; t++) {
        float v = xv[t];
#pragma unroll
        for (int k = 0; k < 64; k++) acc[k] = fmaf(v, w0s[k * 9 + t], acc[k]);
    }
    uint4* op = (uint4*)(yout + ((size_t)pxg << 6));
#pragma unroll
    for (int c8 = 0; c8 < 8; c8++) {
        uint4 o;
        o.x = (unsigned)f2h(acc[c8 * 8 + 0]) | ((unsigned)f2h(acc[c8 * 8 + 1]) << 16);
        o.y = (unsigned)f2h(acc[c8 * 8 + 2]) | ((unsigned)f2h(acc[c8 * 8 + 3]) << 16);
        o.z = (unsigned)f2h(acc[c8 * 8 + 4]) | ((unsigned)f2h(acc[c8 * 8 + 5]) << 16);
        o.w = (unsigned)f2h(acc[c8 * 8 + 6]) | ((unsigned)f2h(acc[c8 * 8 + 7]) << 16);
        op[c8] = o;
    }
}

// ---- stats over NHWC f16 raw activations, coalesced uint4 loads
__global__ __launch_bounds__(256) void stats0_kernel(const u16* __restrict__ yin, float* __restrict__ partial) {
    __shared__ float red[4][64][2];
    int tid = threadIdx.x;
    int tile = blockIdx.x, b = blockIdx.y;
    int pxl = tid >> 3, c8 = tid & 7;
    float s[8], s2[8];
#pragma unroll
    for (int i = 0; i < 8; i++) { s[i] = 0.f; s2[i] = 0.f; }
    for (int it = 0; it < 8; it++) {
        int px = (tile << 8) + (it << 5) + pxl;
        f16x8 v = *(const f16x8*)(yin + ((((size_t)(b << 16)) + px) << 6) + (c8 << 3));
#pragma unroll
        for (int i = 0; i < 8; i++) {
            float f = (float)v[i];
            s[i] += f; s2[i] += f * f;
        }
    }
#pragma unroll
    for (int msk = 8; msk <= 32; msk <<= 1)
#pragma unroll
        for (int i = 0; i < 8; i++) {
            s[i] += __shfl_xor(s[i], msk);
            s2[i] += __shfl_xor(s2[i], msk);
        }
    int lane = tid & 63, wv = tid >> 6;
    if (lane < 8) {
#pragma unroll
        for (int i = 0; i < 8; i++) {
            red[wv][lane * 8 + i][0] = s[i];
            red[wv][lane * 8 + i][1] = s2[i];
        }
    }
    __syncthreads();
    if (tid < 128) {
        int oc = tid >> 1, k2 = tid & 1;
        float v = red[0][oc][k2] + red[1][oc][k2] + red[2][oc][k2] + red[3][oc][k2];
        partial[(((b << 8) + tile) << 7) + (oc << 1) + k2] = v;
    }
}

// ---- reduce per-tile partials -> norm params (inv, -mean*inv)
__global__ void statfin_kernel(const float* __restrict__ partial, float* __restrict__ normp) {
    int idx = blockIdx.x * 256 + threadIdx.x;
    if (idx >= B_ * C_) return;
    int b = idx >> 6, oc = idx & 63;
    float s = 0.f, s2 = 0.f;
    for (int t = 0; t < 256; t++) {
        const float* p = partial + ((b << 8) + t) * 128 + oc * 2;
        s += p[0]; s2 += p[1];
    }
    float mean = s * (1.0f / HW_);
    float var = s2 * (1.0f / HW_) - mean * mean;
    float inv = rsqrtf(var + EPS_);
    normp[idx * 2] = inv;
    normp[idx * 2 + 1] = -mean * inv;
}

// ---- mid conv 64->64 via MFMA implicit GEMM; weights from global (L1), no in-loop barriers
__global__ __launch_bounds__(256, 3) void conv_mid_kernel(
    const u16* __restrict__ yin, const float* __restrict__ normp,
    const u16* __restrict__ wH, const float* __restrict__ bias,
    u16* __restrict__ yout, float* __restrict__ partial) {
    __shared__ u16 s_in[324 * 64];      // 41472 B, ic-chunk XOR-swizzled by (px&7)
    __shared__ unsigned s_invk[32];     // packed f16 pairs (inv)
    __shared__ unsigned s_betak[32];    // packed f16 pairs (beta)
    __shared__ float s_bias[64];
    __shared__ float s_red[4][64][2];

    int tid = threadIdx.x;
    int tile = blockIdx.x, b = blockIdx.y;
    int ty = tile >> 4, tx = tile & 15;
    int y0 = ty << 4, x0 = tx << 4;

    if (tid < 64) s_bias[tid] = bias[tid];
    if (tid < 32) {
        float4 ld = ((const float4*)(normp + (b << 7)))[tid];
        union { unsigned u; f16x2 h; } iv, bv;
        iv.h = (f16x2){(_Float16)ld.x, (_Float16)ld.z};
        bv.h = (f16x2){(_Float16)ld.y, (_Float16)ld.w};
        s_invk[tid] = iv.u;
        s_betak[tid] = bv.u;
    }
    __syncthreads();

    // stage 18x18 halo, packed-f16 norm + lrelu, replicate clamp, swizzled
    for (int chunk = tid; chunk < 2592; chunk += 256) {
        int px = chunk >> 3, c8 = chunk & 7;
        int row = px / 18;
        int col = px - row * 18;
        int iy = clampi(y0 - 1 + row, 0, 255);
        int ix = clampi(x0 - 1 + col, 0, 255);
        union { uint4 q; f16x2 h2[4]; } ui, uo;
        ui.q = *(const uint4*)(yin + ((((size_t)(b << 16)) + (iy << 8) + ix) << 6) + (c8 << 3));
#pragma unroll
        for (int p = 0; p < 4; p++) {
            union { unsigned u; f16x2 h; } iv, bv;
            iv.u = s_invk[(c8 << 2) + p];
            bv.u = s_betak[(c8 << 2) + p];
            f16x2 a = ui.h2[p] * iv.h + bv.h;
            uo.h2[p] = lrelu2(a);
        }
        int phys = c8 ^ (px & 7);
        *(uint4*)(&s_in[(px << 6) + (phys << 3)]) = uo.q;
    }
    __syncthreads();

    int lane = tid & 63, wv = tid >> 6;
    int m = lane & 15, q = lane >> 4;
    int r0 = wv << 2;

    f32x4 acc[4][4];
#pragma unroll
    for (int a = 0; a < 4; a++)
#pragma unroll
        for (int c = 0; c < 4; c++) acc[a][c] = (f32x4){0.f, 0.f, 0.f, 0.f};

#pragma unroll 1
    for (int t = 0; t < 9; t++) {
        int ky = t / 3, kx = t - ky * 3;
        const f16x8* wfp = (const f16x8*)(wH + (t << 12));
        f16x8 wf[8];
#pragma unroll
        for (int f = 0; f < 8; f++) wf[f] = wfp[(f << 6) + lane];
#pragma unroll
        for (int nt = 0; nt < 4; nt++) {
            int row = r0 + nt + ky;
            int p = row * 18 + kx + m;
            int key = p & 7;
            const u16* pin = &s_in[p << 6];
            f16x8 bf0 = *(const f16x8*)(pin + ((q ^ key) << 3));
            f16x8 bf1 = *(const f16x8*)(pin + (((4 + q) ^ key) << 3));
#pragma unroll
            for (int mt = 0; mt < 4; mt++)
                acc[mt][nt] = __builtin_amdgcn_mfma_f32_16x16x32_f16(wf[mt], bf0, acc[mt][nt], 0, 0, 0);
#pragma unroll
            for (int mt = 0; mt < 4; mt++)
                acc[mt][nt] = __builtin_amdgcn_mfma_f32_16x16x32_f16(wf[4 + mt], bf1, acc[mt][nt], 0, 0, 0);
        }
    }

    // epilogue: bias, NHWC f16 store, per-oc stats
    float ss[4][4], sq[4][4];
#pragma unroll
    for (int mt = 0; mt < 4; mt++)
#pragma unroll
        for (int r = 0; r < 4; r++) { ss[mt][r] = 0.f; sq[mt][r] = 0.f; }

#pragma unroll
    for (int mt = 0; mt < 4; mt++) {
        int ocb = (mt << 4) + (q << 2);
        float b0v = s_bias[ocb], b1v = s_bias[ocb + 1], b2v = s_bias[ocb + 2], b3v = s_bias[ocb + 3];
#pragma unroll
        for (int nt = 0; nt < 4; nt++) {
            f32x4 v = acc[mt][nt];
            float v0 = v.x + b0v, v1 = v.y + b1v, v2 = v.z + b2v, v3 = v.w + b3v;
            uint2 o;
            o.x = (unsigned)f2h(v0) | ((unsigned)f2h(v1) << 16);
            o.y = (unsigned)f2h(v2) | ((unsigned)f2h(v3) << 16);
            int y = y0 + r0 + nt, x = x0 + m;
            *(uint2*)(yout + ((((size_t)(b << 16)) + (y << 8) + x) << 6) + ocb) = o;
            ss[mt][0] += v0; ss[mt][1] += v1; ss[mt][2] += v2; ss[mt][3] += v3;
            sq[mt][0] += v0 * v0; sq[mt][1] += v1 * v1; sq[mt][2] += v2 * v2; sq[mt][3] += v3 * v3;
        }
    }
#pragma unroll
    for (int mt = 0; mt < 4; mt++)
#pragma unroll
        for (int r = 0; r < 4; r++) {
#pragma unroll
            for (int msk = 1; msk <= 8; msk <<= 1) {
                ss[mt][r] += __shfl_xor(ss[mt][r], msk);
                sq[mt][r] += __shfl_xor(sq[mt][r], msk);
            }
        }
    if (m == 0) {
#pragma unroll
        for (int mt = 0; mt < 4; mt++)
#pragma unroll
            for (int r = 0; r < 4; r++) {
                int oc = (mt << 4) + (q << 2) + r;
                s_red[wv][oc][0] = ss[mt][r];
                s_red[wv][oc][1] = sq[mt][r];
            }
    }
    __syncthreads();
    if (tid < 128) {
        int oc = tid >> 1, k2 = tid & 1;
        float v = s_red[0][oc][k2] + s_red[1][oc][k2] + s_red[2][oc][k2] + s_red[3][oc][k2];
        partial[(((b << 8) + tile) << 7) + (oc << 1) + k2] = v;
    }
}

// ---- projection 64->1 + residual, LDS-staged tile version
__global__ __launch_bounds__(256, 3) void proj_kernel(
    const u16* __restrict__ y7, const float* __restrict__ normp,
    const float* __restrict__ wp, const float* __restrict__ bp,
    const float* __restrict__ xin, float* __restrict__ out) {
    __shared__ u16 s_in[324 * 64];
    __shared__ unsigned s_invk[32];
    __shared__ unsigned s_betak[32];
    __shared__ float wps[576];

    int tid = threadIdx.x;
    int tile = blockIdx.x, b = blockIdx.y;
    int ty = tile >> 4, tx = tile & 15;
    int y0 = ty << 4, x0 = tx << 4;

    for (int i = tid; i < 576; i += 256) wps[i] = wp[i];
    if (tid < 32) {
        float4 ld = ((const float4*)(normp + (b << 7)))[tid];
        union { unsigned u; f16x2 h; } iv, bv;
        iv.h = (f16x2){(_Float16)ld.x, (_Float16)ld.z};
        bv.h = (f16x2){(_Float16)ld.y, (_Float16)ld.w};
        s_invk[tid] = iv.u;
        s_betak[tid] = bv.u;
    }
    __syncthreads();

    for (int chunk = tid; chunk < 2592; chunk += 256) {
        int px = chunk >> 3, c8 = chunk & 7;
        int row = px / 18;
        int col = px - row * 18;
        int iy = clampi(y0 - 1 + row, 0, 255);
        int ix = clampi(x0 - 1 + col, 0, 255);
        union { uint4 q; f16x2 h2[4]; } ui, uo;
        ui.q = *(const uint4*)(y7 + ((((size_t)(b << 16)) + (iy << 8) + ix) << 6) + (c8 << 3));
#pragma unroll
        for (int p = 0; p < 4; p++) {
            union { unsigned u; f16x2 h; } iv, bv;
            iv.u = s_invk[(c8 << 2) + p];
            bv.u = s_betak[(c8 << 2) + p];
            f16x2 a = ui.h2[p] * iv.h + bv.h;
            uo.h2[p] = lrelu2(a);
        }
        int phys = c8 ^ (px & 7);
        *(uint4*)(&s_in[(px << 6) + (phys << 3)]) = uo.q;
    }
    __syncthreads();

    int py = tid >> 4, pxx = tid & 15;
    float acc = bp[0];
#pragma unroll
    for (int ky = 0; ky < 3; ky++)
#pragma unroll
        for (int kx = 0; kx < 3; kx++) {
            int p = (py + ky) * 18 + pxx + kx;
            int key = p & 7;
            const u16* pin = &s_in[p << 6];
            int t = ky * 3 + kx;
#pragma unroll
            for (int c8 = 0; c8 < 8; c8++) {
                f16x8 v = *(const f16x8*)(pin + ((c8 ^ key) << 3));
#pragma unroll
                for (int i = 0; i < 8; i++)
                    acc = fmaf((float)v[i], wps[(c8 * 8 + i) * 9 + t], acc);
            }
        }
    int pxg = (b << 16) + ((y0 + py) << 8) + x0 + pxx;
    out[pxg] = acc + xin[pxg];
}

// ---- loss: per (offset,b) sum & sumsq of d = crop - t
__global__ __launch_bounds__(256) void loss_main_kernel(
    const float* __restrict__ hr, const float* __restrict__ target,
    float* __restrict__ lossS) {
    int off = blockIdx.x, b = blockIdx.y;
    int oy = off / 13, ox = off - oy * 13;
    const float* hp = hr + b * HW_ + (oy << 8) + ox;
    const float* tp = target + b * HW_ + (6 << 8) + 6;
    float s = 0.f, s2 = 0.f;
    for (int i = threadIdx.x; i < CROP_ * CROP_; i += 256) {
        int y = i / CROP_;
        int x = i - y * CROP_;
        float d = hp[(y << 8) + x] - tp[(y << 8) + x];
        s += d; s2 += d * d;
    }
    __shared__ float rs[4], rs2[4];
#pragma unroll
    for (int msk = 1; msk < 64; msk <<= 1) { s += __shfl_xor(s, msk); s2 += __shfl_xor(s2, msk); }
    int lane = threadIdx.x & 63, wv = threadIdx.x >> 6;
    if (lane == 0) { rs[wv] = s; rs2[wv] = s2; }
    __syncthreads();
    if (threadIdx.x == 0) {
        lossS[(off * 8 + b) * 2] = rs[0] + rs[1] + rs[2] + rs[3];
        lossS[(off * 8 + b) * 2 + 1] = rs2[0] + rs2[1] + rs2[2] + rs2[3];
    }
}

__global__ void loss_final_kernel(const float* __restrict__ lossS, float* __restrict__ out) {
    int b = threadIdx.x;
    float mn = 0.f;
    if (b < 8) {
        mn = 1e30f;
        for (int off = 0; off < 169; off++) {
            float s = lossS[(off * 8 + b) * 2];
            float s2 = lossS[(off * 8 + b) * 2 + 1];
            float m = s * (1.0f / NPIX_);
            float L = s2 * (1.0f / NPIX_) - m * m;
            mn = fminf(mn, L);
        }
    }
#pragma unroll
    for (int msk = 1; msk < 8; msk <<= 1) mn += __shfl_xor(mn, msk);
    if (b == 0) out[0] = mn * 0.125f;
}

extern "C" void kernel_launch(void* const* d_in, const int* in_sizes, int n_in,
                              void* d_out, int out_size, void* d_ws, size_t ws_size,
                              hipStream_t stream) {
    const float* xIn    = (const float*)d_in[0];
    const float* target = (const float*)d_in[1];
    const float* w0     = (const float*)d_in[2];
    const float* b0     = (const float*)d_in[3];
    const float* wsAll  = (const float*)d_in[4];
    const float* bsAll  = (const float*)d_in[5];
    const float* wp     = (const float*)d_in[6];
    const float* bp     = (const float*)d_in[7];
    float* out = (float*)d_out;

    float* normp   = (float*)d_ws;                 // 1,024 f
    float* partial = normp + 1024;                 // 262,144 f
    float* lossS   = partial + 262144;             // 2,704 f
    u16*  wH       = (u16*)(lossS + 2704);         // 258,048 u16
    u16*  bufA     = wH + 258048;                  // 33,554,432 u16 (64 MiB)
    u16*  bufB     = bufA + 33554432;              // 33,554,432 u16 (64 MiB)

    wtrans_kernel<<<1008, 256, 0, stream>>>(wsAll, wH);
    conv0_kernel<<<2048, 256, 0, stream>>>(xIn, w0, b0, bufA);
    stats0_kernel<<<dim3(256, 8), 256, 0, stream>>>(bufA, partial);
    statfin_kernel<<<2, 256, 0, stream>>>(partial, normp);
    for (int l = 0; l < 7; l++) {
        const u16* in = (l & 1) ? bufB : bufA;
        u16* o = (l & 1) ? bufA : bufB;
        conv_mid_kernel<<<dim3(256, 8), 256, 0, stream>>>(
            in, normp, wH + l * 36864, bsAll + l * 64, o, partial);
        statfin_kernel<<<2, 256, 0, stream>>>(partial, normp);
    }
    proj_kernel<<<dim3(256, 8), 256, 0, stream>>>(bufB, normp, wp, bp, xIn, out);
    loss_main_kernel<<<dim3(169, 8), 256, 0, stream>>>(out, target, lossS);
    loss_final_kernel<<<1, 64, 0, stream>>>(lossS, out + 524288);
}

// Round 7
// 1021.905 us; speedup vs baseline: 1.0024x; 1.0024x over previous
//
#include <hip/hip_runtime.h>

#define B_ 8
#define C_ 64
#define HW_ 65536
#define SLOPE_ 0.01f
#define EPS_ 1e-5f
#define CROP_ 244
#define NPIX_ 59536.0f

typedef unsigned short u16;
typedef __attribute__((ext_vector_type(8))) _Float16 f16x8;
typedef __attribute__((ext_vector_type(2))) _Float16 f16x2;
typedef __attribute__((ext_vector_type(4))) float f32x4;

__device__ __forceinline__ int clampi(int v, int lo, int hi) { return v < lo ? lo : (v > hi ? hi : v); }

__device__ __forceinline__ u16 f2h(float f) {
    union { _Float16 h; u16 u; } v; v.h = (_Float16)f; return v.u;
}
__device__ __forceinline__ float h2f(u16 b) {
    union { u16 u; _Float16 h; } v; v.u = b; return (float)v.h;
}
__device__ __forceinline__ f16x2 lrelu2(f16x2 a) {
    const f16x2 z = {(_Float16)0.f, (_Float16)0.f};
    const f16x2 sl = {(_Float16)SLOPE_, (_Float16)SLOPE_};
    return __builtin_elementwise_max(a, z) + sl * __builtin_elementwise_min(a, z);
}

// ---- weight pack: ws (7,oc64,ic64,3,3) fp32 -> wH f16 frag-major
// wH[l][tap][kb][mt][lane][j]: oc = mt*16 + (lane&15), ic = kb*32 + (lane>>4)*8 + j
__global__ void wtrans_kernel(const float* __restrict__ ws, u16* __restrict__ wH) {
    int idx = blockIdx.x * 256 + threadIdx.x;
    if (idx >= 7 * 36864) return;
    int l = idx / 36864;
    int rem = idx - l * 36864;
    int frag = rem >> 9;          // tap*8 + kb*4 + mt
    int lj = rem & 511;
    int lane = lj >> 3, j = lj & 7;
    int tap = frag >> 3, kb = (frag >> 2) & 1, mt = frag & 3;
    int oc = (mt << 4) + (lane & 15);
    int ic = (kb << 5) + ((lane >> 4) << 3) + j;
    wH[idx] = f2h(ws[((l * 64 + oc) * 64 + ic) * 9 + tap]);
}

// ---- conv0: 1->64, NHWC f16 output
__global__ __launch_bounds__(256) void conv0_kernel(
    const float* __restrict__ xin, const float* __restrict__ w0,
    const float* __restrict__ b0, u16* __restrict__ yout) {
    __shared__ float w0s[576];
    __shared__ float b0s[64];
    int tid = threadIdx.x;
    for (int i = tid; i < 576; i += 256) w0s[i] = w0[i];
    if (tid < 64) b0s[tid] = b0[tid];
    __syncthreads();
    // XCD swizzle: b = bid & 7
    int b = blockIdx.x & 7;
    int px = (blockIdx.x >> 3) * 256 + tid;
    int pxg = (b << 16) + px;
    int y = px >> 8, x = px & 255;
    float xv[9];
#pragma unroll
    for (int ky = 0; ky < 3; ky++)
#pragma unroll
        for (int kx = 0; kx < 3; kx++)
            xv[ky * 3 + kx] = xin[(b << 16) + (clampi(y + ky - 1, 0, 255) << 8) + clampi(x + kx - 1, 0, 255)];
    float acc[64];
#pragma unroll
    for (int k = 0; k < 64; k++) acc[k] = b0s[k];
#pragma unroll
    for (int t = 0; t < 9; t++) {
        float v = xv[t];
#pragma unroll
        for (int k = 0; k < 64; k++) acc[k] = fmaf(v, w0s[k * 9 + t], acc[k]);
    }
    uint4* op = (uint4*)(yout + ((size_t)pxg << 6));
#pragma unroll
    for (int c8 = 0; c8 < 8; c8++) {
        uint4 o;
        o.x = (unsigned)f2h(acc[c8 * 8 + 0]) | ((unsigned)f2h(acc[c8 * 8 + 1]) << 16);
        o.y = (unsigned)f2h(acc[c8 * 8 + 2]) | ((unsigned)f2h(acc[c8 * 8 + 3]) << 16);
        o.z = (unsigned)f2h(acc[c8 * 8 + 4]) | ((unsigned)f2h(acc[c8 * 8 + 5]) << 16);
        o.w = (unsigned)f2h(acc[c8 * 8 + 6]) | ((unsigned)f2h(acc[c8 * 8 + 7]) << 16);
        op[c8] = o;
    }
}

// ---- stats over NHWC f16 raw activations, coalesced uint4 loads, XCD-swizzled
__global__ __launch_bounds__(256) void stats0_kernel(const u16* __restrict__ yin, float* __restrict__ partial) {
    __shared__ float red[4][64][2];
    int tid = threadIdx.x;
    int b = blockIdx.x & 7, tile = blockIdx.x >> 3;
    int pxl = tid >> 3, c8 = tid & 7;
    float s[8], s2[8];
#pragma unroll
    for (int i = 0; i < 8; i++) { s[i] = 0.f; s2[i] = 0.f; }
    for (int it = 0; it < 8; it++) {
        int px = (tile << 8) + (it << 5) + pxl;
        f16x8 v = *(const f16x8*)(yin + ((((size_t)(b << 16)) + px) << 6) + (c8 << 3));
#pragma unroll
        for (int i = 0; i < 8; i++) {
            float f = (float)v[i];
            s[i] += f; s2[i] += f * f;
        }
    }
#pragma unroll
    for (int msk = 8; msk <= 32; msk <<= 1)
#pragma unroll
        for (int i = 0; i < 8; i++) {
            s[i] += __shfl_xor(s[i], msk);
            s2[i] += __shfl_xor(s2[i], msk);
        }
    int lane = tid & 63, wv = tid >> 6;
    if (lane < 8) {
#pragma unroll
        for (int i = 0; i < 8; i++) {
            red[wv][lane * 8 + i][0] = s[i];
            red[wv][lane * 8 + i][1] = s2[i];
        }
    }
    __syncthreads();
    if (tid < 128) {
        int oc = tid >> 1, k2 = tid & 1;
        float v = red[0][oc][k2] + red[1][oc][k2] + red[2][oc][k2] + red[3][oc][k2];
        partial[(((b << 8) + tile) << 7) + (oc << 1) + k2] = v;
    }
}

// ---- reduce per-tile partials -> norm params (inv, -mean*inv)
__global__ void statfin_kernel(const float* __restrict__ partial, float* __restrict__ normp) {
    int idx = blockIdx.x * 256 + threadIdx.x;
    if (idx >= B_ * C_) return;
    int b = idx >> 6, oc = idx & 63;
    float s = 0.f, s2 = 0.f;
    for (int t = 0; t < 256; t++) {
        const float* p = partial + ((b << 8) + t) * 128 + oc * 2;
        s += p[0]; s2 += p[1];
    }
    float mean = s * (1.0f / HW_);
    float var = s2 * (1.0f / HW_) - mean * mean;
    float inv = rsqrtf(var + EPS_);
    normp[idx * 2] = inv;
    normp[idx * 2 + 1] = -mean * inv;
}

// ---- mid conv 64->64 via MFMA implicit GEMM; XCD-swizzled (image b = XCD)
__global__ __launch_bounds__(256, 3) void conv_mid_kernel(
    const u16* __restrict__ yin, const float* __restrict__ normp,
    const u16* __restrict__ wH, const float* __restrict__ bias,
    u16* __restrict__ yout, float* __restrict__ partial) {
    __shared__ u16 s_in[324 * 64];      // 41472 B, ic-chunk XOR-swizzled by (px&7)
    __shared__ unsigned s_invk[32];     // packed f16 pairs (inv)
    __shared__ unsigned s_betak[32];    // packed f16 pairs (beta)
    __shared__ float s_bias[64];
    __shared__ float s_red[4][64][2];

    int tid = threadIdx.x;
    int b = blockIdx.x & 7;             // XCD k <-> image k
    int tile = blockIdx.x >> 3;         // row-major tiles within image
    int ty = tile >> 4, tx = tile & 15;
    int y0 = ty << 4, x0 = tx << 4;

    if (tid < 64) s_bias[tid] = bias[tid];
    if (tid < 32) {
        float4 ld = ((const float4*)(normp + (b << 7)))[tid];
        union { unsigned u; f16x2 h; } iv, bv;
        iv.h = (f16x2){(_Float16)ld.x, (_Float16)ld.z};
        bv.h = (f16x2){(_Float16)ld.y, (_Float16)ld.w};
        s_invk[tid] = iv.u;
        s_betak[tid] = bv.u;
    }
    __syncthreads();

    // stage 18x18 halo, packed-f16 norm + lrelu, replicate clamp, swizzled
    for (int chunk = tid; chunk < 2592; chunk += 256) {
        int px = chunk >> 3, c8 = chunk & 7;
        int row = px / 18;
        int col = px - row * 18;
        int iy = clampi(y0 - 1 + row, 0, 255);
        int ix = clampi(x0 - 1 + col, 0, 255);
        union { uint4 q; f16x2 h2[4]; } ui, uo;
        ui.q = *(const uint4*)(yin + ((((size_t)(b << 16)) + (iy << 8) + ix) << 6) + (c8 << 3));
#pragma unroll
        for (int p = 0; p < 4; p++) {
            union { unsigned u; f16x2 h; } iv, bv;
            iv.u = s_invk[(c8 << 2) + p];
            bv.u = s_betak[(c8 << 2) + p];
            f16x2 a = ui.h2[p] * iv.h + bv.h;
            uo.h2[p] = lrelu2(a);
        }
        int phys = c8 ^ (px & 7);
        *(uint4*)(&s_in[(px << 6) + (phys << 3)]) = uo.q;
    }
    __syncthreads();

    int lane = tid & 63, wv = tid >> 6;
    int m = lane & 15, q = lane >> 4;
    int r0 = wv << 2;

    f32x4 acc[4][4];
#pragma unroll
    for (int a = 0; a < 4; a++)
#pragma unroll
        for (int c = 0; c < 4; c++) acc[a][c] = (f32x4){0.f, 0.f, 0.f, 0.f};

#pragma unroll 1
    for (int t = 0; t < 9; t++) {
        int ky = t / 3, kx = t - ky * 3;
        const f16x8* wfp = (const f16x8*)(wH + (t << 12));
        f16x8 wf[8];
#pragma unroll
        for (int f = 0; f < 8; f++) wf[f] = wfp[(f << 6) + lane];
#pragma unroll
        for (int nt = 0; nt < 4; nt++) {
            int row = r0 + nt + ky;
            int p = row * 18 + kx + m;
            int key = p & 7;
            const u16* pin = &s_in[p << 6];
            f16x8 bf0 = *(const f16x8*)(pin + ((q ^ key) << 3));
            f16x8 bf1 = *(const f16x8*)(pin + (((4 + q) ^ key) << 3));
#pragma unroll
            for (int mt = 0; mt < 4; mt++)
                acc[mt][nt] = __builtin_amdgcn_mfma_f32_16x16x32_f16(wf[mt], bf0, acc[mt][nt], 0, 0, 0);
#pragma unroll
            for (int mt = 0; mt < 4; mt++)
                acc[mt][nt] = __builtin_amdgcn_mfma_f32_16x16x32_f16(wf[4 + mt], bf1, acc[mt][nt], 0, 0, 0);
        }
    }

    // epilogue: bias, NHWC f16 store, per-oc stats
    float ss[4][4], sq[4][4];
#pragma unroll
    for (int mt = 0; mt < 4; mt++)
#pragma unroll
        for (int r = 0; r < 4; r++) { ss[mt][r] = 0.f; sq[mt][r] = 0.f; }

#pragma unroll
    for (int mt = 0; mt < 4; mt++) {
        int ocb = (mt << 4) + (q << 2);
        float b0v = s_bias[ocb], b1v = s_bias[ocb + 1], b2v = s_bias[ocb + 2], b3v = s_bias[ocb + 3];
#pragma unroll
        for (int nt = 0; nt < 4; nt++) {
            f32x4 v = acc[mt][nt];
            float v0 = v.x + b0v, v1 = v.y + b1v, v2 = v.z + b2v, v3 = v.w + b3v;
            uint2 o;
            o.x = (unsigned)f2h(v0) | ((unsigned)f2h(v1) << 16);
            o.y = (unsigned)f2h(v2) | ((unsigned)f2h(v3) << 16);
            int y = y0 + r0 + nt, x = x0 + m;
            *(uint2*)(yout + ((((size_t)(b << 16)) + (y << 8) + x) << 6) + ocb) = o;
            ss[mt][0] += v0; ss[mt][1] += v1; ss[mt][2] += v2; ss[mt][3] += v3;
            sq[mt][0] += v0 * v0; sq[mt][1] += v1 * v1; sq[mt][2] += v2 * v2; sq[mt][3] += v3 * v3;
        }
    }
#pragma unroll
    for (int mt = 0; mt < 4; mt++)
#pragma unroll
        for (int r = 0; r < 4; r++) {
#pragma unroll
            for (int msk = 1; msk <= 8; msk <<= 1) {
                ss[mt][r] += __shfl_xor(ss[mt][r], msk);
                sq[mt][r] += __shfl_xor(sq[mt][r], msk);
            }
        }
    if (m == 0) {
#pragma unroll
        for (int mt = 0; mt < 4; mt++)
#pragma unroll
            for (int r = 0; r < 4; r++) {
                int oc = (mt << 4) + (q << 2) + r;
                s_red[wv][oc][0] = ss[mt][r];
                s_red[wv][oc][1] = sq[mt][r];
            }
    }
    __syncthreads();
    if (tid < 128) {
        int oc = tid >> 1, k2 = tid & 1;
        float v = s_red[0][oc][k2] + s_red[1][oc][k2] + s_red[2][oc][k2] + s_red[3][oc][k2];
        partial[(((b << 8) + tile) << 7) + (oc << 1) + k2] = v;
    }
}

// ---- projection 64->1 + residual, LDS-staged, XCD-swizzled
__global__ __launch_bounds__(256, 3) void proj_kernel(
    const u16* __restrict__ y7, const float* __restrict__ normp,
    const float* __restrict__ wp, const float* __restrict__ bp,
    const float* __restrict__ xin, float* __restrict__ out) {
    __shared__ u16 s_in[324 * 64];
    __shared__ unsigned s_invk[32];
    __shared__ unsigned s_betak[32];
    __shared__ float wps[576];

    int tid = threadIdx.x;
    int b = blockIdx.x & 7, tile = blockIdx.x >> 3;
    int ty = tile >> 4, tx = tile & 15;
    int y0 = ty << 4, x0 = tx << 4;

    for (int i = tid; i < 576; i += 256) wps[i] = wp[i];
    if (tid < 32) {
        float4 ld = ((const float4*)(normp + (b << 7)))[tid];
        union { unsigned u; f16x2 h; } iv, bv;
        iv.h = (f16x2){(_Float16)ld.x, (_Float16)ld.z};
        bv.h = (f16x2){(_Float16)ld.y, (_Float16)ld.w};
        s_invk[tid] = iv.u;
        s_betak[tid] = bv.u;
    }
    __syncthreads();

    for (int chunk = tid; chunk < 2592; chunk += 256) {
        int px = chunk >> 3, c8 = chunk & 7;
        int row = px / 18;
        int col = px - row * 18;
        int iy = clampi(y0 - 1 + row, 0, 255);
        int ix = clampi(x0 - 1 + col, 0, 255);
        union { uint4 q; f16x2 h2[4]; } ui, uo;
        ui.q = *(const uint4*)(y7 + ((((size_t)(b << 16)) + (iy << 8) + ix) << 6) + (c8 << 3));
#pragma unroll
        for (int p = 0; p < 4; p++) {
            union { unsigned u; f16x2 h; } iv, bv;
            iv.u = s_invk[(c8 << 2) + p];
            bv.u = s_betak[(c8 << 2) + p];
            f16x2 a = ui.h2[p] * iv.h + bv.h;
            uo.h2[p] = lrelu2(a);
        }
        int phys = c8 ^ (px & 7);
        *(uint4*)(&s_in[(px << 6) + (phys << 3)]) = uo.q;
    }
    __syncthreads();

    int py = tid >> 4, pxx = tid & 15;
    float acc = bp[0];
#pragma unroll
    for (int ky = 0; ky < 3; ky++)
#pragma unroll
        for (int kx = 0; kx < 3; kx++) {
            int p = (py + ky) * 18 + pxx + kx;
            int key = p & 7;
            const u16* pin = &s_in[p << 6];
            int t = ky * 3 + kx;
#pragma unroll
            for (int c8 = 0; c8 < 8; c8++) {
                f16x8 v = *(const f16x8*)(pin + ((c8 ^ key) << 3));
#pragma unroll
                for (int i = 0; i < 8; i++)
                    acc = fmaf((float)v[i], wps[(c8 * 8 + i) * 9 + t], acc);
            }
        }
    int pxg = (b << 16) + ((y0 + py) << 8) + x0 + pxx;
    out[pxg] = acc + xin[pxg];
}

// ---- loss: per (offset,b) sum & sumsq of d = crop - t, XCD-swizzled
__global__ __launch_bounds__(256) void loss_main_kernel(
    const float* __restrict__ hr, const float* __restrict__ target,
    float* __restrict__ lossS) {
    int b = blockIdx.x & 7, off = blockIdx.x >> 3;
    int oy = off / 13, ox = off - oy * 13;
    const float* hp = hr + b * HW_ + (oy << 8) + ox;
    const float* tp = target + b * HW_ + (6 << 8) + 6;
    float s = 0.f, s2 = 0.f;
    for (int i = threadIdx.x; i < CROP_ * CROP_; i += 256) {
        int y = i / CROP_;
        int x = i - y * CROP_;
        float d = hp[(y << 8) + x] - tp[(y << 8) + x];
        s += d; s2 += d * d;
    }
    __shared__ float rs[4], rs2[4];
#pragma unroll
    for (int msk = 1; msk < 64; msk <<= 1) { s += __shfl_xor(s, msk); s2 += __shfl_xor(s2, msk); }
    int lane = threadIdx.x & 63, wv = threadIdx.x >> 6;
    if (lane == 0) { rs[wv] = s; rs2[wv] = s2; }
    __syncthreads();
    if (threadIdx.x == 0) {
        lossS[(off * 8 + b) * 2] = rs[0] + rs[1] + rs[2] + rs[3];
        lossS[(off * 8 + b) * 2 + 1] = rs2[0] + rs2[1] + rs2[2] + rs2[3];
    }
}

__global__ void loss_final_kernel(const float* __restrict__ lossS, float* __restrict__ out) {
    int b = threadIdx.x;
    float mn = 0.f;
    if (b < 8) {
        mn = 1e30f;
        for (int off = 0; off < 169; off++) {
            float s = lossS[(off * 8 + b) * 2];
            float s2 = lossS[(off * 8 + b) * 2 + 1];
            float m = s * (1.0f / NPIX_);
            float L = s2 * (1.0f / NPIX_) - m * m;
            mn = fminf(mn, L);
        }
    }
#pragma unroll
    for (int msk = 1; msk < 8; msk <<= 1) mn += __shfl_xor(mn, msk);
    if (b == 0) out[0] = mn * 0.125f;
}

extern "C" void kernel_launch(void* const* d_in, const int* in_sizes, int n_in,
                              void* d_out, int out_size, void* d_ws, size_t ws_size,
                              hipStream_t stream) {
    const float* xIn    = (const float*)d_in[0];
    const float* target = (const float*)d_in[1];
    const float* w0     = (const float*)d_in[2];
    const float* b0     = (const float*)d_in[3];
    const float* wsAll  = (const float*)d_in[4];
    const float* bsAll  = (const float*)d_in[5];
    const float* wp     = (const float*)d_in[6];
    const float* bp     = (const float*)d_in[7];
    float* out = (float*)d_out;

    float* normp   = (float*)d_ws;                 // 1,024 f
    float* partial = normp + 1024;                 // 262,144 f
    float* lossS   = partial + 262144;             // 2,704 f
    u16*  wH       = (u16*)(lossS + 2704);         // 258,048 u16
    u16*  bufA     = wH + 258048;                  // 33,554,432 u16 (64 MiB)
    u16*  bufB     = bufA + 33554432;              // 33,554,432 u16 (64 MiB)

    wtrans_kernel<<<1008, 256, 0, stream>>>(wsAll, wH);
    conv0_kernel<<<2048, 256, 0, stream>>>(xIn, w0, b0, bufA);
    stats0_kernel<<<2048, 256, 0, stream>>>(bufA, partial);
    statfin_kernel<<<2, 256, 0, stream>>>(partial, normp);
    for (int l = 0; l < 7; l++) {
        const u16* in = (l & 1) ? bufB : bufA;
        u16* o = (l & 1) ? bufA : bufB;
        conv_mid_kernel<<<2048, 256, 0, stream>>>(
            in, normp, wH + l * 36864, bsAll + l * 64, o, partial);
        statfin_kernel<<<2, 256, 0, stream>>>(partial, normp);
    }
    proj_kernel<<<2048, 256, 0, stream>>>(bufB, normp, wp, bp, xIn, out);
    loss_main_kernel<<<1352, 256, 0, stream>>>(out, target, lossS);
    loss_final_kernel<<<1, 64, 0, stream>>>(lossS, out + 524288);
}

// Round 8
// 763.148 us; speedup vs baseline: 1.3423x; 1.3391x over previous
//
#include <hip/hip_runtime.h>

#define B_ 8
#define C_ 64
#define HW_ 65536
#define SLOPE_ 0.01f
#define EPS_ 1e-5f
#define CROP_ 244
#define NPIX_ 59536.0f

typedef unsigned short u16;
typedef __attribute__((ext_vector_type(8))) _Float16 f16x8;
typedef __attribute__((ext_vector_type(2))) _Float16 f16x2;
typedef __attribute__((ext_vector_type(4))) float f32x4;

__device__ __forceinline__ int clampi(int v, int lo, int hi) { return v < lo ? lo : (v > hi ? hi : v); }

__device__ __forceinline__ u16 f2h(float f) {
    union { _Float16 h; u16 u; } v; v.h = (_Float16)f; return v.u;
}
__device__ __forceinline__ float h2f(u16 b) {
    union { u16 u; _Float16 h; } v; v.u = b; return (float)v.h;
}
__device__ __forceinline__ f16x2 lrelu2(f16x2 a) {
    const f16x2 z = {(_Float16)0.f, (_Float16)0.f};
    const f16x2 sl = {(_Float16)SLOPE_, (_Float16)SLOPE_};
    return __builtin_elementwise_max(a, z) + sl * __builtin_elementwise_min(a, z);
}

// ---- weight pack: ws (7,oc64,ic64,3,3) fp32 -> wH f16 frag-major
// wH[l][tap][kb][mt][lane][j]: oc = mt*16 + (lane&15), ic = kb*32 + (lane>>4)*8 + j
__global__ void wtrans_kernel(const float* __restrict__ ws, u16* __restrict__ wH) {
    int idx = blockIdx.x * 256 + threadIdx.x;
    if (idx >= 7 * 36864) return;
    int l = idx / 36864;
    int rem = idx - l * 36864;
    int frag = rem >> 9;          // tap*8 + kb*4 + mt
    int lj = rem & 511;
    int lane = lj >> 3, j = lj & 7;
    int tap = frag >> 3, kb = (frag >> 2) & 1, mt = frag & 3;
    int oc = (mt << 4) + (lane & 15);
    int ic = (kb << 5) + ((lane >> 4) << 3) + j;
    wH[idx] = f2h(ws[((l * 64 + oc) * 64 + ic) * 9 + tap]);
}

// ---- conv0: 1->64, NHWC f16 output
__global__ __launch_bounds__(256) void conv0_kernel(
    const float* __restrict__ xin, const float* __restrict__ w0,
    const float* __restrict__ b0, u16* __restrict__ yout) {
    __shared__ float w0s[576];
    __shared__ float b0s[64];
    int tid = threadIdx.x;
    for (int i = tid; i < 576; i += 256) w0s[i] = w0[i];
    if (tid < 64) b0s[tid] = b0[tid];
    __syncthreads();
    int b = blockIdx.x & 7;
    int px = (blockIdx.x >> 3) * 256 + tid;
    int pxg = (b << 16) + px;
    int y = px >> 8, x = px & 255;
    float xv[9];
#pragma unroll
    for (int ky = 0; ky < 3; ky++)
#pragma unroll
        for (int kx = 0; kx < 3; kx++)
            xv[ky * 3 + kx] = xin[(b << 16) + (clampi(y + ky - 1, 0, 255) << 8) + clampi(x + kx - 1, 0, 255)];
    float acc[64];
#pragma unroll
    for (int k = 0; k < 64; k++) acc[k] = b0s[k];
#pragma unroll
    for (int t = 0; t < 9; t++) {
        float v = xv[t];
#pragma unroll
        for (int k = 0; k < 64; k++) acc[k] = fmaf(v, w0s[k * 9 + t], acc[k]);
    }
    uint4* op = (uint4*)(yout + ((size_t)pxg << 6));
#pragma unroll
    for (int c8 = 0; c8 < 8; c8++) {
        uint4 o;
        o.x = (unsigned)f2h(acc[c8 * 8 + 0]) | ((unsigned)f2h(acc[c8 * 8 + 1]) << 16);
        o.y = (unsigned)f2h(acc[c8 * 8 + 2]) | ((unsigned)f2h(acc[c8 * 8 + 3]) << 16);
        o.z = (unsigned)f2h(acc[c8 * 8 + 4]) | ((unsigned)f2h(acc[c8 * 8 + 5]) << 16);
        o.w = (unsigned)f2h(acc[c8 * 8 + 6]) | ((unsigned)f2h(acc[c8 * 8 + 7]) << 16);
        op[c8] = o;
    }
}

// ---- stats over NHWC f16 raw activations
__global__ __launch_bounds__(256) void stats0_kernel(const u16* __restrict__ yin, float* __restrict__ partial) {
    __shared__ float red[4][64][2];
    int tid = threadIdx.x;
    int b = blockIdx.x & 7, tile = blockIdx.x >> 3;
    int pxl = tid >> 3, c8 = tid & 7;
    float s[8], s2[8];
#pragma unroll
    for (int i = 0; i < 8; i++) { s[i] = 0.f; s2[i] = 0.f; }
    for (int it = 0; it < 8; it++) {
        int px = (tile << 8) + (it << 5) + pxl;
        f16x8 v = *(const f16x8*)(yin + ((((size_t)(b << 16)) + px) << 6) + (c8 << 3));
#pragma unroll
        for (int i = 0; i < 8; i++) {
            float f = (float)v[i];
            s[i] += f; s2[i] += f * f;
        }
    }
#pragma unroll
    for (int msk = 8; msk <= 32; msk <<= 1)
#pragma unroll
        for (int i = 0; i < 8; i++) {
            s[i] += __shfl_xor(s[i], msk);
            s2[i] += __shfl_xor(s2[i], msk);
        }
    int lane = tid & 63, wv = tid >> 6;
    if (lane < 8) {
#pragma unroll
        for (int i = 0; i < 8; i++) {
            red[wv][lane * 8 + i][0] = s[i];
            red[wv][lane * 8 + i][1] = s2[i];
        }
    }
    __syncthreads();
    if (tid < 128) {
        int oc = tid >> 1, k2 = tid & 1;
        float v = red[0][oc][k2] + red[1][oc][k2] + red[2][oc][k2] + red[3][oc][k2];
        partial[(((b << 8) + tile) << 7) + (oc << 1) + k2] = v;
    }
}

// ---- parallel statfin: 512 blocks (b,oc) x 1 wave
__global__ __launch_bounds__(64) void statfin_kernel(const float* __restrict__ partial, float* __restrict__ normp) {
    int b = blockIdx.x >> 6, oc = blockIdx.x & 63;
    int lane = threadIdx.x;
    float s = 0.f, s2 = 0.f;
#pragma unroll
    for (int i = 0; i < 4; i++) {
        int t = lane + (i << 6);
        const float* p = partial + (((b << 8) + t) << 7) + (oc << 1);
        s += p[0]; s2 += p[1];
    }
#pragma unroll
    for (int msk = 1; msk < 64; msk <<= 1) { s += __shfl_xor(s, msk); s2 += __shfl_xor(s2, msk); }
    if (lane == 0) {
        float mean = s * (1.0f / HW_);
        float var = s2 * (1.0f / HW_) - mean * mean;
        float inv = rsqrtf(var + EPS_);
        normp[blockIdx.x * 2] = inv;
        normp[blockIdx.x * 2 + 1] = -mean * inv;
    }
}

// ---- mid conv 64->64 via MFMA implicit GEMM; weight frags reg-double-buffered
__global__ __launch_bounds__(256, 3) void conv_mid_kernel(
    const u16* __restrict__ yin, const float* __restrict__ normp,
    const u16* __restrict__ wH, const float* __restrict__ bias,
    u16* __restrict__ yout, float* __restrict__ partial) {
    __shared__ u16 s_in[324 * 64];      // 41472 B, ic-chunk XOR-swizzled by (px&7)
    __shared__ unsigned s_invk[32];
    __shared__ unsigned s_betak[32];
    __shared__ float s_bias[64];
    __shared__ float s_red[4][64][2];

    int tid = threadIdx.x;
    int b = blockIdx.x & 7;
    int tile = blockIdx.x >> 3;
    int ty = tile >> 4, tx = tile & 15;
    int y0 = ty << 4, x0 = tx << 4;

    if (tid < 64) s_bias[tid] = bias[tid];
    if (tid < 32) {
        float4 ld = ((const float4*)(normp + (b << 7)))[tid];
        union { unsigned u; f16x2 h; } iv, bv;
        iv.h = (f16x2){(_Float16)ld.x, (_Float16)ld.z};
        bv.h = (f16x2){(_Float16)ld.y, (_Float16)ld.w};
        s_invk[tid] = iv.u;
        s_betak[tid] = bv.u;
    }
    __syncthreads();

    for (int chunk = tid; chunk < 2592; chunk += 256) {
        int px = chunk >> 3, c8 = chunk & 7;
        int row = px / 18;
        int col = px - row * 18;
        int iy = clampi(y0 - 1 + row, 0, 255);
        int ix = clampi(x0 - 1 + col, 0, 255);
        union { uint4 q; f16x2 h2[4]; } ui, uo;
        ui.q = *(const uint4*)(yin + ((((size_t)(b << 16)) + (iy << 8) + ix) << 6) + (c8 << 3));
#pragma unroll
        for (int p = 0; p < 4; p++) {
            union { unsigned u; f16x2 h; } iv, bv;
            iv.u = s_invk[(c8 << 2) + p];
            bv.u = s_betak[(c8 << 2) + p];
            f16x2 a = ui.h2[p] * iv.h + bv.h;
            uo.h2[p] = lrelu2(a);
        }
        int phys = c8 ^ (px & 7);
        *(uint4*)(&s_in[(px << 6) + (phys << 3)]) = uo.q;
    }
    __syncthreads();

    int lane = tid & 63, wv = tid >> 6;
    int m = lane & 15, q = lane >> 4;
    int r0 = wv << 2;

    f32x4 acc[4][4];
#pragma unroll
    for (int a = 0; a < 4; a++)
#pragma unroll
        for (int c = 0; c < 4; c++) acc[a][c] = (f32x4){0.f, 0.f, 0.f, 0.f};

    const f16x8* wfp = (const f16x8*)wH;
    f16x8 wcur[8], wnxt[8];
#pragma unroll
    for (int f = 0; f < 8; f++) wcur[f] = wfp[(f << 6) + lane];

#pragma unroll 1
    for (int t = 0; t < 9; t++) {
        if (t < 8) {
            const f16x8* wn = wfp + ((t + 1) << 9);
#pragma unroll
            for (int f = 0; f < 8; f++) wnxt[f] = wn[(f << 6) + lane];
        }
        int ky = t / 3, kx = t - ky * 3;
#pragma unroll
        for (int nt = 0; nt < 4; nt++) {
            int row = r0 + nt + ky;
            int p = row * 18 + kx + m;
            int key = p & 7;
            const u16* pin = &s_in[p << 6];
            f16x8 bf0 = *(const f16x8*)(pin + ((q ^ key) << 3));
            f16x8 bf1 = *(const f16x8*)(pin + (((4 + q) ^ key) << 3));
#pragma unroll
            for (int mt = 0; mt < 4; mt++)
                acc[mt][nt] = __builtin_amdgcn_mfma_f32_16x16x32_f16(wcur[mt], bf0, acc[mt][nt], 0, 0, 0);
#pragma unroll
            for (int mt = 0; mt < 4; mt++)
                acc[mt][nt] = __builtin_amdgcn_mfma_f32_16x16x32_f16(wcur[4 + mt], bf1, acc[mt][nt], 0, 0, 0);
        }
        if (t < 8) {
#pragma unroll
            for (int f = 0; f < 8; f++) wcur[f] = wnxt[f];
        }
    }

    // epilogue: bias, NHWC f16 store, per-oc stats
    float ss[4][4], sq[4][4];
#pragma unroll
    for (int mt = 0; mt < 4; mt++)
#pragma unroll
        for (int r = 0; r < 4; r++) { ss[mt][r] = 0.f; sq[mt][r] = 0.f; }

#pragma unroll
    for (int mt = 0; mt < 4; mt++) {
        int ocb = (mt << 4) + (q << 2);
        float b0v = s_bias[ocb], b1v = s_bias[ocb + 1], b2v = s_bias[ocb + 2], b3v = s_bias[ocb + 3];
#pragma unroll
        for (int nt = 0; nt < 4; nt++) {
            f32x4 v = acc[mt][nt];
            float v0 = v.x + b0v, v1 = v.y + b1v, v2 = v.z + b2v, v3 = v.w + b3v;
            uint2 o;
            o.x = (unsigned)f2h(v0) | ((unsigned)f2h(v1) << 16);
            o.y = (unsigned)f2h(v2) | ((unsigned)f2h(v3) << 16);
            int y = y0 + r0 + nt, x = x0 + m;
            *(uint2*)(yout + ((((size_t)(b << 16)) + (y << 8) + x) << 6) + ocb) = o;
            ss[mt][0] += v0; ss[mt][1] += v1; ss[mt][2] += v2; ss[mt][3] += v3;
            sq[mt][0] += v0 * v0; sq[mt][1] += v1 * v1; sq[mt][2] += v2 * v2; sq[mt][3] += v3 * v3;
        }
    }
#pragma unroll
    for (int mt = 0; mt < 4; mt++)
#pragma unroll
        for (int r = 0; r < 4; r++) {
#pragma unroll
            for (int msk = 1; msk <= 8; msk <<= 1) {
                ss[mt][r] += __shfl_xor(ss[mt][r], msk);
                sq[mt][r] += __shfl_xor(sq[mt][r], msk);
            }
        }
    if (m == 0) {
#pragma unroll
        for (int mt = 0; mt < 4; mt++)
#pragma unroll
            for (int r = 0; r < 4; r++) {
                int oc = (mt << 4) + (q << 2) + r;
                s_red[wv][oc][0] = ss[mt][r];
                s_red[wv][oc][1] = sq[mt][r];
            }
    }
    __syncthreads();
    if (tid < 128) {
        int oc = tid >> 1, k2 = tid & 1;
        float v = s_red[0][oc][k2] + s_red[1][oc][k2] + s_red[2][oc][k2] + s_red[3][oc][k2];
        partial[(((b << 8) + tile) << 7) + (oc << 1) + k2] = v;
    }
}

// ---- projection 64->1 + residual: 16x64 slab per block, channel-chunked
__global__ __launch_bounds__(256) void proj_kernel(
    const u16* __restrict__ y7, const float* __restrict__ normp,
    const float* __restrict__ wp, const float* __restrict__ bp,
    const float* __restrict__ xin, float* __restrict__ out) {
    __shared__ u16 s_a[18 * 66 * 8];     // 19008 B
    __shared__ unsigned s_invk[32];
    __shared__ unsigned s_betak[32];
    __shared__ unsigned s_w2[288];       // f16x2-packed wp: [pair0..31][tap0..8]

    int tid = threadIdx.x;
    int b = blockIdx.x & 7, slab = blockIdx.x >> 3;
    int sy = slab >> 2, sx = slab & 3;
    int y0 = sy << 4, x0 = sx << 6;

    if (tid < 32) {
        float4 ld = ((const float4*)(normp + (b << 7)))[tid];
        union { unsigned u; f16x2 h; } iv, bv;
        iv.h = (f16x2){(_Float16)ld.x, (_Float16)ld.z};
        bv.h = (f16x2){(_Float16)ld.y, (_Float16)ld.w};
        s_invk[tid] = iv.u;
        s_betak[tid] = bv.u;
    }
    for (int i = tid; i < 288; i += 256) {
        int pr = i / 9, tap = i - pr * 9;
        int ch = pr << 1;
        s_w2[i] = (unsigned)f2h(wp[ch * 9 + tap]) | ((unsigned)f2h(wp[(ch + 1) * 9 + tap]) << 16);
    }
    __syncthreads();

    int col = tid & 63, prow = tid >> 6;
    float acc[4];
#pragma unroll
    for (int r = 0; r < 4; r++) acc[r] = bp[0];

    for (int c8 = 0; c8 < 8; c8++) {
        // stage 18x66 pixels of this 8-channel chunk (norm+lrelu fused)
        for (int idx = tid; idx < 1188; idx += 256) {
            int row = idx / 66;
            int cc = idx - row * 66;
            int iy = clampi(y0 - 1 + row, 0, 255);
            int ix = clampi(x0 - 1 + cc, 0, 255);
            union { uint4 q; f16x2 h2[4]; } ui, uo;
            ui.q = *(const uint4*)(y7 + ((((size_t)(b << 16)) + (iy << 8) + ix) << 6) + (c8 << 3));
#pragma unroll
            for (int p = 0; p < 4; p++) {
                union { unsigned u; f16x2 h; } iv, bv;
                iv.u = s_invk[(c8 << 2) + p];
                bv.u = s_betak[(c8 << 2) + p];
                uo.h2[p] = lrelu2(ui.h2[p] * iv.h + bv.h);
            }
            *(uint4*)(&s_a[idx << 3]) = uo.q;
        }
        __syncthreads();

#pragma unroll
        for (int ky = 0; ky < 3; ky++)
#pragma unroll
            for (int kx = 0; kx < 3; kx++) {
                int tap = ky * 3 + kx;
                float w[8];
#pragma unroll
                for (int p = 0; p < 4; p++) {
                    unsigned wu = s_w2[((c8 << 2) + p) * 9 + tap];
                    w[2 * p] = h2f((u16)(wu & 0xffff));
                    w[2 * p + 1] = h2f((u16)(wu >> 16));
                }
#pragma unroll
                for (int rr = 0; rr < 4; rr++) {
                    int lrow = prow * 4 + rr + ky;
                    f16x8 v = *(const f16x8*)(&s_a[(lrow * 66 + col + kx) << 3]);
#pragma unroll
                    for (int i = 0; i < 8; i++)
                        acc[rr] = fmaf((float)v[i], w[i], acc[rr]);
                }
            }
        __syncthreads();
    }

#pragma unroll
    for (int rr = 0; rr < 4; rr++) {
        int pxg = (b << 16) + ((y0 + prow * 4 + rr) << 8) + x0 + col;
        out[pxg] = acc[rr] + xin[pxg];
    }
}

// ---- loss: per (offset,b) sum & sumsq of d = crop - t
__global__ __launch_bounds__(256) void loss_main_kernel(
    const float* __restrict__ hr, const float* __restrict__ target,
    float* __restrict__ lossS) {
    int b = blockIdx.x & 7, off = blockIdx.x >> 3;
    int oy = off / 13, ox = off - oy * 13;
    const float* hp = hr + b * HW_ + (oy << 8) + ox;
    const float* tp = target + b * HW_ + (6 << 8) + 6;
    float s = 0.f, s2 = 0.f;
    for (int i = threadIdx.x; i < CROP_ * CROP_; i += 256) {
        int y = i / CROP_;
        int x = i - y * CROP_;
        float d = hp[(y << 8) + x] - tp[(y << 8) + x];
        s += d; s2 += d * d;
    }
    __shared__ float rs[4], rs2[4];
#pragma unroll
    for (int msk = 1; msk < 64; msk <<= 1) { s += __shfl_xor(s, msk); s2 += __shfl_xor(s2, msk); }
    int lane = threadIdx.x & 63, wv = threadIdx.x >> 6;
    if (lane == 0) { rs[wv] = s; rs2[wv] = s2; }
    __syncthreads();
    if (threadIdx.x == 0) {
        lossS[(off * 8 + b) * 2] = rs[0] + rs[1] + rs[2] + rs[3];
        lossS[(off * 8 + b) * 2 + 1] = rs2[0] + rs2[1] + rs2[2] + rs2[3];
    }
}

__global__ void loss_final_kernel(const float* __restrict__ lossS, float* __restrict__ out) {
    int b = threadIdx.x;
    float mn = 0.f;
    if (b < 8) {
        mn = 1e30f;
        for (int off = 0; off < 169; off++) {
            float s = lossS[(off * 8 + b) * 2];
            float s2 = lossS[(off * 8 + b) * 2 + 1];
            float m = s * (1.0f / NPIX_);
            float L = s2 * (1.0f / NPIX_) - m * m;
            mn = fminf(mn, L);
        }
    }
#pragma unroll
    for (int msk = 1; msk < 8; msk <<= 1) mn += __shfl_xor(mn, msk);
    if (b == 0) out[0] = mn * 0.125f;
}

extern "C" void kernel_launch(void* const* d_in, const int* in_sizes, int n_in,
                              void* d_out, int out_size, void* d_ws, size_t ws_size,
                              hipStream_t stream) {
    const float* xIn    = (const float*)d_in[0];
    const float* target = (const float*)d_in[1];
    const float* w0     = (const float*)d_in[2];
    const float* b0     = (const float*)d_in[3];
    const float* wsAll  = (const float*)d_in[4];
    const float* bsAll  = (const float*)d_in[5];
    const float* wp     = (const float*)d_in[6];
    const float* bp     = (const float*)d_in[7];
    float* out = (float*)d_out;

    float* normp   = (float*)d_ws;                 // 1,024 f
    float* partial = normp + 1024;                 // 262,144 f
    float* lossS   = partial + 262144;             // 2,704 f
    u16*  wH       = (u16*)(lossS + 2704);         // 258,048 u16
    u16*  bufA     = wH + 258048;                  // 33,554,432 u16 (64 MiB)
    u16*  bufB     = bufA + 33554432;              // 33,554,432 u16 (64 MiB)

    wtrans_kernel<<<1008, 256, 0, stream>>>(wsAll, wH);
    conv0_kernel<<<2048, 256, 0, stream>>>(xIn, w0, b0, bufA);
    stats0_kernel<<<2048, 256, 0, stream>>>(bufA, partial);
    statfin_kernel<<<512, 64, 0, stream>>>(partial, normp);
    for (int l = 0; l < 7; l++) {
        const u16* in = (l & 1) ? bufB : bufA;
        u16* o = (l & 1) ? bufA : bufB;
        conv_mid_kernel<<<2048, 256, 0, stream>>>(
            in, normp, wH + l * 36864, bsAll + l * 64, o, partial);
        statfin_kernel<<<512, 64, 0, stream>>>(partial, normp);
    }
    proj_kernel<<<512, 256, 0, stream>>>(bufB, normp, wp, bp, xIn, out);
    loss_main_kernel<<<1352, 256, 0, stream>>>(out, target, lossS);
    loss_final_kernel<<<1, 64, 0, stream>>>(lossS, out + 524288);
}

// Round 9
// 730.036 us; speedup vs baseline: 1.4031x; 1.0454x over previous
//
#include <hip/hip_runtime.h>

#define B_ 8
#define C_ 64
#define HW_ 65536
#define SLOPE_ 0.01f
#define EPS_ 1e-5f
#define CROP_ 244
#define NPIX_ 59536.0f

typedef unsigned short u16;
typedef __attribute__((ext_vector_type(8))) _Float16 f16x8;
typedef __attribute__((ext_vector_type(2))) _Float16 f16x2;
typedef __attribute__((ext_vector_type(4))) float f32x4;

__device__ __forceinline__ int clampi(int v, int lo, int hi) { return v < lo ? lo : (v > hi ? hi : v); }

__device__ __forceinline__ u16 f2h(float f) {
    union { _Float16 h; u16 u; } v; v.h = (_Float16)f; return v.u;
}
__device__ __forceinline__ float h2f(u16 b) {
    union { u16 u; _Float16 h; } v; v.u = b; return (float)v.h;
}
__device__ __forceinline__ f16x2 lrelu2(f16x2 a) {
    const f16x2 z = {(_Float16)0.f, (_Float16)0.f};
    const f16x2 sl = {(_Float16)SLOPE_, (_Float16)SLOPE_};
    return __builtin_elementwise_max(a, z) + sl * __builtin_elementwise_min(a, z);
}

// ---- weight pack: ws (7,oc64,ic64,3,3) fp32 -> wH f16 frag-major
__global__ void wtrans_kernel(const float* __restrict__ ws, u16* __restrict__ wH) {
    int idx = blockIdx.x * 256 + threadIdx.x;
    if (idx >= 7 * 36864) return;
    int l = idx / 36864;
    int rem = idx - l * 36864;
    int frag = rem >> 9;          // tap*8 + kb*4 + mt
    int lj = rem & 511;
    int lane = lj >> 3, j = lj & 7;
    int tap = frag >> 3, kb = (frag >> 2) & 1, mt = frag & 3;
    int oc = (mt << 4) + (lane & 15);
    int ic = (kb << 5) + ((lane >> 4) << 3) + j;
    wH[idx] = f2h(ws[((l * 64 + oc) * 64 + ic) * 9 + tap]);
}

// ---- conv0: 1->64, NHWC f16 output
__global__ __launch_bounds__(256) void conv0_kernel(
    const float* __restrict__ xin, const float* __restrict__ w0,
    const float* __restrict__ b0, u16* __restrict__ yout) {
    __shared__ float w0s[576];
    __shared__ float b0s[64];
    int tid = threadIdx.x;
    for (int i = tid; i < 576; i += 256) w0s[i] = w0[i];
    if (tid < 64) b0s[tid] = b0[tid];
    __syncthreads();
    int b = blockIdx.x & 7;
    int px = (blockIdx.x >> 3) * 256 + tid;
    int pxg = (b << 16) + px;
    int y = px >> 8, x = px & 255;
    float xv[9];
#pragma unroll
    for (int ky = 0; ky < 3; ky++)
#pragma unroll
        for (int kx = 0; kx < 3; kx++)
            xv[ky * 3 + kx] = xin[(b << 16) + (clampi(y + ky - 1, 0, 255) << 8) + clampi(x + kx - 1, 0, 255)];
    float acc[64];
#pragma unroll
    for (int k = 0; k < 64; k++) acc[k] = b0s[k];
#pragma unroll
    for (int t = 0; t < 9; t++) {
        float v = xv[t];
#pragma unroll
        for (int k = 0; k < 64; k++) acc[k] = fmaf(v, w0s[k * 9 + t], acc[k]);
    }
    uint4* op = (uint4*)(yout + ((size_t)pxg << 6));
#pragma unroll
    for (int c8 = 0; c8 < 8; c8++) {
        uint4 o;
        o.x = (unsigned)f2h(acc[c8 * 8 + 0]) | ((unsigned)f2h(acc[c8 * 8 + 1]) << 16);
        o.y = (unsigned)f2h(acc[c8 * 8 + 2]) | ((unsigned)f2h(acc[c8 * 8 + 3]) << 16);
        o.z = (unsigned)f2h(acc[c8 * 8 + 4]) | ((unsigned)f2h(acc[c8 * 8 + 5]) << 16);
        o.w = (unsigned)f2h(acc[c8 * 8 + 6]) | ((unsigned)f2h(acc[c8 * 8 + 7]) << 16);
        op[c8] = o;
    }
}

// ---- stats over NHWC f16 raw activations (256 tiles/image)
__global__ __launch_bounds__(256) void stats0_kernel(const u16* __restrict__ yin, float* __restrict__ partial) {
    __shared__ float red[4][64][2];
    int tid = threadIdx.x;
    int b = blockIdx.x & 7, tile = blockIdx.x >> 3;
    int pxl = tid >> 3, c8 = tid & 7;
    float s[8], s2[8];
#pragma unroll
    for (int i = 0; i < 8; i++) { s[i] = 0.f; s2[i] = 0.f; }
    for (int it = 0; it < 8; it++) {
        int px = (tile << 8) + (it << 5) + pxl;
        f16x8 v = *(const f16x8*)(yin + ((((size_t)(b << 16)) + px) << 6) + (c8 << 3));
#pragma unroll
        for (int i = 0; i < 8; i++) {
            float f = (float)v[i];
            s[i] += f; s2[i] += f * f;
        }
    }
#pragma unroll
    for (int msk = 8; msk <= 32; msk <<= 1)
#pragma unroll
        for (int i = 0; i < 8; i++) {
            s[i] += __shfl_xor(s[i], msk);
            s2[i] += __shfl_xor(s2[i], msk);
        }
    int lane = tid & 63, wv = tid >> 6;
    if (lane < 8) {
#pragma unroll
        for (int i = 0; i < 8; i++) {
            red[wv][lane * 8 + i][0] = s[i];
            red[wv][lane * 8 + i][1] = s2[i];
        }
    }
    __syncthreads();
    if (tid < 128) {
        int oc = tid >> 1, k2 = tid & 1;
        float v = red[0][oc][k2] + red[1][oc][k2] + red[2][oc][k2] + red[3][oc][k2];
        partial[(((b << 8) + tile) << 7) + (oc << 1) + k2] = v;
    }
}

// ---- parallel statfin: 512 blocks (b,oc) x 1 wave; ntiles variable
__global__ __launch_bounds__(64) void statfin_kernel(const float* __restrict__ partial, float* __restrict__ normp, int ntiles) {
    int b = blockIdx.x >> 6, oc = blockIdx.x & 63;
    int lane = threadIdx.x;
    float s = 0.f, s2 = 0.f;
    for (int t = lane; t < ntiles; t += 64) {
        const float* p = partial + (((size_t)(b * ntiles + t)) << 7) + (oc << 1);
        s += p[0]; s2 += p[1];
    }
#pragma unroll
    for (int msk = 1; msk < 64; msk <<= 1) { s += __shfl_xor(s, msk); s2 += __shfl_xor(s2, msk); }
    if (lane == 0) {
        float mean = s * (1.0f / HW_);
        float var = s2 * (1.0f / HW_) - mean * mean;
        float inv = rsqrtf(var + EPS_);
        normp[blockIdx.x * 2] = inv;
        normp[blockIdx.x * 2 + 1] = -mean * inv;
    }
}

// ---- mid conv 64->64 via MFMA; 32x16 tile, halo 34x18, 2 blocks/CU
__global__ __launch_bounds__(256, 2) void conv_mid_kernel(
    const u16* __restrict__ yin, const float* __restrict__ normp,
    const u16* __restrict__ wH, const float* __restrict__ bias,
    u16* __restrict__ yout, float* __restrict__ partial) {
    __shared__ u16 s_in[612 * 64];      // 78336 B; 34 rows x 18 cols, swizzled by (px&7)
    __shared__ unsigned s_invk[32];
    __shared__ unsigned s_betak[32];
    __shared__ float s_bias[64];
    float* s_red = (float*)s_in;        // aliased after compute: [4][64][2]

    int tid = threadIdx.x;
    int b = blockIdx.x & 7;
    int tile = blockIdx.x >> 3;         // 0..127
    int ty = tile >> 4, tx = tile & 15; // ty 0..7 (32-row bands), tx 0..15 (16-col)
    int y0 = ty << 5, x0 = tx << 4;

    if (tid < 64) s_bias[tid] = bias[tid];
    if (tid < 32) {
        float4 ld = ((const float4*)(normp + (b << 7)))[tid];
        union { unsigned u; f16x2 h; } iv, bv;
        iv.h = (f16x2){(_Float16)ld.x, (_Float16)ld.z};
        bv.h = (f16x2){(_Float16)ld.y, (_Float16)ld.w};
        s_invk[tid] = iv.u;
        s_betak[tid] = bv.u;
    }
    __syncthreads();

    // stage 34x18 halo, packed-f16 norm + lrelu, replicate clamp, swizzled
    for (int chunk = tid; chunk < 4896; chunk += 256) {
        int px = chunk >> 3, c8 = chunk & 7;
        int row = px / 18;
        int col = px - row * 18;
        int iy = clampi(y0 - 1 + row, 0, 255);
        int ix = clampi(x0 - 1 + col, 0, 255);
        union { uint4 q; f16x2 h2[4]; } ui, uo;
        ui.q = *(const uint4*)(yin + ((((size_t)(b << 16)) + (iy << 8) + ix) << 6) + (c8 << 3));
#pragma unroll
        for (int p = 0; p < 4; p++) {
            union { unsigned u; f16x2 h; } iv, bv;
            iv.u = s_invk[(c8 << 2) + p];
            bv.u = s_betak[(c8 << 2) + p];
            uo.h2[p] = lrelu2(ui.h2[p] * iv.h + bv.h);
        }
        int phys = c8 ^ (px & 7);
        *(uint4*)(&s_in[(px << 6) + (phys << 3)]) = uo.q;
    }
    __syncthreads();

    int lane = tid & 63, wv = tid >> 6;
    int m = lane & 15, q = lane >> 4;
    int r0 = wv << 3;                   // 8 rows per wave

    f32x4 acc[4][8];
#pragma unroll
    for (int a = 0; a < 4; a++)
#pragma unroll
        for (int c = 0; c < 8; c++) acc[a][c] = (f32x4){0.f, 0.f, 0.f, 0.f};

    const f16x8* wfp = (const f16x8*)wH;
#pragma unroll 1
    for (int t = 0; t < 9; t++) {
        int ky = t / 3, kx = t - ky * 3;
        const f16x8* wn = wfp + (t << 9);
        f16x8 wf[8];
#pragma unroll
        for (int f = 0; f < 8; f++) wf[f] = wn[(f << 6) + lane];
#pragma unroll
        for (int nt = 0; nt < 8; nt++) {
            int p = (r0 + nt + ky) * 18 + kx + m;
            int key = p & 7;
            const u16* pin = &s_in[p << 6];
            f16x8 bf0 = *(const f16x8*)(pin + ((q ^ key) << 3));
            f16x8 bf1 = *(const f16x8*)(pin + (((4 + q) ^ key) << 3));
#pragma unroll
            for (int mt = 0; mt < 4; mt++)
                acc[mt][nt] = __builtin_amdgcn_mfma_f32_16x16x32_f16(wf[mt], bf0, acc[mt][nt], 0, 0, 0);
#pragma unroll
            for (int mt = 0; mt < 4; mt++)
                acc[mt][nt] = __builtin_amdgcn_mfma_f32_16x16x32_f16(wf[4 + mt], bf1, acc[mt][nt], 0, 0, 0);
        }
    }
    __syncthreads();   // s_in dead; s_red alias becomes safe

    // epilogue: bias, NHWC f16 store, per-oc stats
    float ss[4][4], sq[4][4];
#pragma unroll
    for (int mt = 0; mt < 4; mt++)
#pragma unroll
        for (int r = 0; r < 4; r++) { ss[mt][r] = 0.f; sq[mt][r] = 0.f; }

#pragma unroll
    for (int mt = 0; mt < 4; mt++) {
        int ocb = (mt << 4) + (q << 2);
        float b0v = s_bias[ocb], b1v = s_bias[ocb + 1], b2v = s_bias[ocb + 2], b3v = s_bias[ocb + 3];
#pragma unroll
        for (int nt = 0; nt < 8; nt++) {
            f32x4 v = acc[mt][nt];
            float v0 = v.x + b0v, v1 = v.y + b1v, v2 = v.z + b2v, v3 = v.w + b3v;
            uint2 o;
            o.x = (unsigned)f2h(v0) | ((unsigned)f2h(v1) << 16);
            o.y = (unsigned)f2h(v2) | ((unsigned)f2h(v3) << 16);
            int y = y0 + r0 + nt, x = x0 + m;
            *(uint2*)(yout + ((((size_t)(b << 16)) + (y << 8) + x) << 6) + ocb) = o;
            ss[mt][0] += v0; ss[mt][1] += v1; ss[mt][2] += v2; ss[mt][3] += v3;
            sq[mt][0] += v0 * v0; sq[mt][1] += v1 * v1; sq[mt][2] += v2 * v2; sq[mt][3] += v3 * v3;
        }
    }
#pragma unroll
    for (int mt = 0; mt < 4; mt++)
#pragma unroll
        for (int r = 0; r < 4; r++) {
#pragma unroll
            for (int msk = 1; msk <= 8; msk <<= 1) {
                ss[mt][r] += __shfl_xor(ss[mt][r], msk);
                sq[mt][r] += __shfl_xor(sq[mt][r], msk);
            }
        }
    if (m == 0) {
#pragma unroll
        for (int mt = 0; mt < 4; mt++)
#pragma unroll
            for (int r = 0; r < 4; r++) {
                int oc = (mt << 4) + (q << 2) + r;
                s_red[(wv * 64 + oc) * 2] = ss[mt][r];
                s_red[(wv * 64 + oc) * 2 + 1] = sq[mt][r];
            }
    }
    __syncthreads();
    if (tid < 128) {
        int oc = tid >> 1, k2 = tid & 1;
        float v = s_red[(0 * 64 + oc) * 2 + k2] + s_red[(1 * 64 + oc) * 2 + k2]
                + s_red[(2 * 64 + oc) * 2 + k2] + s_red[(3 * 64 + oc) * 2 + k2];
        partial[(((b << 7) + tile) << 7) + (oc << 1) + k2] = v;
    }
}

// ---- projection 64->1 + residual: 16x64 slab per block, channel-chunked
__global__ __launch_bounds__(256) void proj_kernel(
    const u16* __restrict__ y7, const float* __restrict__ normp,
    const float* __restrict__ wp, const float* __restrict__ bp,
    const float* __restrict__ xin, float* __restrict__ out) {
    __shared__ u16 s_a[18 * 66 * 8];
    __shared__ unsigned s_invk[32];
    __shared__ unsigned s_betak[32];
    __shared__ unsigned s_w2[288];

    int tid = threadIdx.x;
    int b = blockIdx.x & 7, slab = blockIdx.x >> 3;
    int sy = slab >> 2, sx = slab & 3;
    int y0 = sy << 4, x0 = sx << 6;

    if (tid < 32) {
        float4 ld = ((const float4*)(normp + (b << 7)))[tid];
        union { unsigned u; f16x2 h; } iv, bv;
        iv.h = (f16x2){(_Float16)ld.x, (_Float16)ld.z};
        bv.h = (f16x2){(_Float16)ld.y, (_Float16)ld.w};
        s_invk[tid] = iv.u;
        s_betak[tid] = bv.u;
    }
    for (int i = tid; i < 288; i += 256) {
        int pr = i / 9, tap = i - pr * 9;
        int ch = pr << 1;
        s_w2[i] = (unsigned)f2h(wp[ch * 9 + tap]) | ((unsigned)f2h(wp[(ch + 1) * 9 + tap]) << 16);
    }
    __syncthreads();

    int col = tid & 63, prow = tid >> 6;
    float acc[4];
#pragma unroll
    for (int r = 0; r < 4; r++) acc[r] = bp[0];

    for (int c8 = 0; c8 < 8; c8++) {
        for (int idx = tid; idx < 1188; idx += 256) {
            int row = idx / 66;
            int cc = idx - row * 66;
            int iy = clampi(y0 - 1 + row, 0, 255);
            int ix = clampi(x0 - 1 + cc, 0, 255);
            union { uint4 q; f16x2 h2[4]; } ui, uo;
            ui.q = *(const uint4*)(y7 + ((((size_t)(b << 16)) + (iy << 8) + ix) << 6) + (c8 << 3));
#pragma unroll
            for (int p = 0; p < 4; p++) {
                union { unsigned u; f16x2 h; } iv, bv;
                iv.u = s_invk[(c8 << 2) + p];
                bv.u = s_betak[(c8 << 2) + p];
                uo.h2[p] = lrelu2(ui.h2[p] * iv.h + bv.h);
            }
            *(uint4*)(&s_a[idx << 3]) = uo.q;
        }
        __syncthreads();

#pragma unroll
        for (int ky = 0; ky < 3; ky++)
#pragma unroll
            for (int kx = 0; kx < 3; kx++) {
                int tap = ky * 3 + kx;
                float w[8];
#pragma unroll
                for (int p = 0; p < 4; p++) {
                    unsigned wu = s_w2[((c8 << 2) + p) * 9 + tap];
                    w[2 * p] = h2f((u16)(wu & 0xffff));
                    w[2 * p + 1] = h2f((u16)(wu >> 16));
                }
#pragma unroll
                for (int rr = 0; rr < 4; rr++) {
                    int lrow = prow * 4 + rr + ky;
                    f16x8 v = *(const f16x8*)(&s_a[(lrow * 66 + col + kx) << 3]);
#pragma unroll
                    for (int i = 0; i < 8; i++)
                        acc[rr] = fmaf((float)v[i], w[i], acc[rr]);
                }
            }
        __syncthreads();
    }

#pragma unroll
    for (int rr = 0; rr < 4; rr++) {
        int pxg = (b << 16) + ((y0 + prow * 4 + rr) << 8) + x0 + col;
        out[pxg] = acc[rr] + xin[pxg];
    }
}

// ---- loss stage 1: per (b, strip of 4 rows, oy): accumulate 13 ox offsets from LDS
__global__ __launch_bounds__(256) void loss_strip_kernel(
    const float* __restrict__ hr, const float* __restrict__ target,
    float* __restrict__ partial2) {
    __shared__ float s_hr[4][256];
    __shared__ float s_t[4][244];
    __shared__ float s_r2[4][13][2];

    int tid = threadIdx.x;
    int b = blockIdx.x & 7;
    int rest = blockIdx.x >> 3;     // 0..792
    int oy = rest % 13;
    int strip = rest / 13;          // 0..60
    int y0 = strip << 2;

    for (int i = tid; i < 1024; i += 256) {
        int r = i >> 8, x = i & 255;
        s_hr[r][x] = hr[(b << 16) + ((y0 + oy + r) << 8) + x];
    }
    for (int i = tid; i < 976; i += 256) {
        int r = i / 244, x = i - r * 244;
        s_t[r][x] = target[(b << 16) + ((y0 + r + 6) << 8) + 6 + x];
    }
    __syncthreads();

    float s[13], s2[13];
#pragma unroll
    for (int o = 0; o < 13; o++) { s[o] = 0.f; s2[o] = 0.f; }
    if (tid < 244) {
#pragma unroll
        for (int r = 0; r < 4; r++) {
            float tv = s_t[r][tid];
#pragma unroll
            for (int o = 0; o < 13; o++) {
                float d = s_hr[r][tid + o] - tv;
                s[o] += d; s2[o] += d * d;
            }
        }
    }
#pragma unroll
    for (int msk = 1; msk < 64; msk <<= 1)
#pragma unroll
        for (int o = 0; o < 13; o++) {
            s[o] += __shfl_xor(s[o], msk);
            s2[o] += __shfl_xor(s2[o], msk);
        }
    int lane = tid & 63, wv = tid >> 6;
    if (lane == 0) {
#pragma unroll
        for (int o = 0; o < 13; o++) { s_r2[wv][o][0] = s[o]; s_r2[wv][o][1] = s2[o]; }
    }
    __syncthreads();
    if (tid < 26) {
        int o = tid >> 1, k = tid & 1;
        float v = s_r2[0][o][k] + s_r2[1][o][k] + s_r2[2][o][k] + s_r2[3][o][k];
        int off = oy * 13 + o;
        partial2[(((b * 61 + strip) * 169) + off) * 2 + k] = v;
    }
}

// ---- loss stage 2: reduce 61 strips -> per-(off,b) loss
__global__ __launch_bounds__(64) void loss_mid_kernel(
    const float* __restrict__ partial2, float* __restrict__ lossM) {
    int b = blockIdx.x & 7, off = blockIdx.x >> 3;
    int lane = threadIdx.x;
    float s = 0.f, s2 = 0.f;
    if (lane < 61) {
        const float* p = partial2 + (((b * 61 + lane) * 169) + off) * 2;
        s = p[0]; s2 = p[1];
    }
#pragma unroll
    for (int msk = 1; msk < 64; msk <<= 1) { s += __shfl_xor(s, msk); s2 += __shfl_xor(s2, msk); }
    if (lane == 0) {
        float m = s * (1.0f / NPIX_);
        lossM[off * 8 + b] = s2 * (1.0f / NPIX_) - m * m;
    }
}

__global__ void loss_final_kernel(const float* __restrict__ lossM, float* __restrict__ out) {
    int b = threadIdx.x;
    float mn = 0.f;
    if (b < 8) {
        mn = 1e30f;
        for (int off = 0; off < 169; off++) mn = fminf(mn, lossM[off * 8 + b]);
    }
#pragma unroll
    for (int msk = 1; msk < 8; msk <<= 1) mn += __shfl_xor(mn, msk);
    if (b == 0) out[0] = mn * 0.125f;
}

extern "C" void kernel_launch(void* const* d_in, const int* in_sizes, int n_in,
                              void* d_out, int out_size, void* d_ws, size_t ws_size,
                              hipStream_t stream) {
    const float* xIn    = (const float*)d_in[0];
    const float* target = (const float*)d_in[1];
    const float* w0     = (const float*)d_in[2];
    const float* b0     = (const float*)d_in[3];
    const float* wsAll  = (const float*)d_in[4];
    const float* bsAll  = (const float*)d_in[5];
    const float* wp     = (const float*)d_in[6];
    const float* bp     = (const float*)d_in[7];
    float* out = (float*)d_out;

    float* normp    = (float*)d_ws;                 // 1,024 f
    float* partial  = normp + 1024;                 // 262,144 f
    float* partial2 = partial + 262144;             // 164,944 f
    float* lossM    = partial2 + 164944;            // 1,352 f
    u16*  wH        = (u16*)(lossM + 1352);         // 258,048 u16
    u16*  bufA      = wH + 258048;                  // 64 MiB
    u16*  bufB      = bufA + 33554432;              // 64 MiB

    wtrans_kernel<<<1008, 256, 0, stream>>>(wsAll, wH);
    conv0_kernel<<<2048, 256, 0, stream>>>(xIn, w0, b0, bufA);
    stats0_kernel<<<2048, 256, 0, stream>>>(bufA, partial);
    statfin_kernel<<<512, 64, 0, stream>>>(partial, normp, 256);
    for (int l = 0; l < 7; l++) {
        const u16* in = (l & 1) ? bufB : bufA;
        u16* o = (l & 1) ? bufA : bufB;
        conv_mid_kernel<<<1024, 256, 0, stream>>>(
            in, normp, wH + l * 36864, bsAll + l * 64, o, partial);
        statfin_kernel<<<512, 64, 0, stream>>>(partial, normp, 128);
    }
    proj_kernel<<<512, 256, 0, stream>>>(bufB, normp, wp, bp, xIn, out);
    loss_strip_kernel<<<6344, 256, 0, stream>>>(out, target, partial2);
    loss_mid_kernel<<<1352, 64, 0, stream>>>(partial2, lossM);
    loss_final_kernel<<<1, 64, 0, stream>>>(lossM, out + 524288);
}